// Round 1
// 542.201 us; speedup vs baseline: 1.0891x; 1.0891x over previous
//
#include <hip/hip_runtime.h>
#include <math.h>

// Problem constants (B=16, T=2048, DIM=512, N_EMBED=4096)
#define N_TOK   32768
#define N_CODE  4096
#define DIM     512

// Coarse MFMA tiling: block = 64 tokens x 2048 codes (one N-half)
#define CBM 64
#define NHALF 2048
#define CBN 256                   // codes per nt step
#define CBK 64                    // K chunk per staging round
#define NT_STEPS (NHALF / CBN)    // 8
#define KC_STEPS (DIM / CBK)      // 8
#define SPITCH 36                 // score strip pitch (floats), 16B aligned
#define BUFSZ 40960               // one LDS tile buffer: A 8KB + B 32KB

typedef __bf16 bf16x8 __attribute__((ext_vector_type(8)));
typedef float  f32x4  __attribute__((ext_vector_type(4)));

__device__ __forceinline__ unsigned short f32_to_bf16_rn(float f) {
    union { float f; unsigned int u; } c; c.f = f;
    unsigned int u = c.u;
    return (unsigned short)((u + 0x7FFFu + ((u >> 16) & 1u)) >> 16);
}

// ---------------------------------------------------------------------------
// numpy pairwise f32 sum over 512 contiguous elements (bit-exact), see R3.
__device__ __forceinline__ float pairwise_tree(const float* p) {
    float P[4];
#pragma unroll
    for (int b = 0; b < 4; ++b) {
        float t01 = __fadd_rn(p[b * 8 + 0], p[b * 8 + 1]);
        float t23 = __fadd_rn(p[b * 8 + 2], p[b * 8 + 3]);
        float t45 = __fadd_rn(p[b * 8 + 4], p[b * 8 + 5]);
        float t67 = __fadd_rn(p[b * 8 + 6], p[b * 8 + 7]);
        P[b] = __fadd_rn(__fadd_rn(t01, t23), __fadd_rn(t45, t67));
    }
    return __fadd_rn(__fadd_rn(P[0], P[1]), __fadd_rn(P[2], P[3]));
}

// ---------------------------------------------------------------------------
// K1: per-code f32-replicated norm + t3.
__global__ void norms_kernel(const float* __restrict__ embed,
                             float* __restrict__ n_f,
                             float* __restrict__ t3_f) {
    __shared__ float part[32];
    int j = blockIdx.x;
    int lane = threadIdx.x;
    const float* e = embed + (size_t)j * DIM;

    if (lane < 32) {
        int base = (lane >> 3) * 128 + (lane & 7);
        float v = e[base];
        float r = __fmul_rn(v, v);
#pragma unroll
        for (int i = 1; i < 16; ++i) {
            float u = e[base + 8 * i];
            r = __fadd_rn(r, __fmul_rn(u, u));
        }
        part[lane] = r;
    }
    __syncthreads();
    float S = pairwise_tree(part);
    float n = __fsqrt_rn(S);
    __syncthreads();

    if (lane < 32) {
        int base = (lane >> 3) * 128 + (lane & 7);
        float w0 = __fdiv_rn(e[base], n);
        float r = __fmul_rn(w0, w0);
#pragma unroll
        for (int i = 1; i < 16; ++i) {
            float w = __fdiv_rn(e[base + 8 * i], n);
            r = __fadd_rn(r, __fmul_rn(w, w));
        }
        part[lane] = r;
    }
    __syncthreads();
    if (lane == 0) {
        n_f[j]  = n;
        t3_f[j] = pairwise_tree(part);
    }
}

// ---------------------------------------------------------------------------
// K2a: x -> bf16 (RN)
__global__ void xcvt_kernel(const float* __restrict__ x, unsigned short* __restrict__ xb) {
    int gid = blockIdx.x * 256 + threadIdx.x;
    float4 v = ((const float4*)x)[gid];
    ushort4 o;
    o.x = f32_to_bf16_rn(v.x); o.y = f32_to_bf16_rn(v.y);
    o.z = f32_to_bf16_rn(v.z); o.w = f32_to_bf16_rn(v.w);
    ((ushort4*)xb)[gid] = o;
}

// K2b: w_hat = e/n (f32, np-exact) -> f32 (refine) + bf16 (coarse)
__global__ void wcvt_kernel(const float* __restrict__ embed, const float* __restrict__ n_f,
                            float* __restrict__ whf, unsigned short* __restrict__ wb) {
    int gid = blockIdx.x * 256 + threadIdx.x;
    int row = gid >> 7;
    float n = n_f[row];
    float4 e = ((const float4*)embed)[gid];
    float4 w;
    w.x = __fdiv_rn(e.x, n); w.y = __fdiv_rn(e.y, n);
    w.z = __fdiv_rn(e.z, n); w.w = __fdiv_rn(e.w, n);
    ((float4*)whf)[gid] = w;
    ushort4 o;
    o.x = f32_to_bf16_rn(w.x); o.y = f32_to_bf16_rn(w.y);
    o.z = f32_to_bf16_rn(w.z); o.w = f32_to_bf16_rn(w.w);
    ((ushort4*)wb)[gid] = o;
}

// ---------------------------------------------------------------------------
__device__ __forceinline__ void top8_insert(float s, int idx, float (&bv)[8], int (&bi)[8]) {
    if (s > bv[7]) {
#pragma unroll
        for (int k = 7; k > 0; --k) {
            bool up = s > bv[k - 1];
            float nv = (s > bv[k]) ? s : bv[k];
            int   ni = (s > bv[k]) ? idx : bi[k];
            bv[k] = up ? bv[k - 1] : nv;
            bi[k] = up ? bi[k - 1] : ni;
        }
        bool up0 = s > bv[0];
        bi[0] = up0 ? idx : bi[0];
        bv[0] = up0 ? s : bv[0];
    }
}

// ---------------------------------------------------------------------------
// K3: bf16 MFMA coarse scoring + fused per-token top-8 over one N-half.
// Grid: (N_TOK/64)*2 blocks; block b: tokens (b>>1)*64, codes (b&1)*2048..+2048.
// 4 waves; wave w computes the 64x64 strip at cols nt*256 + w*64.
//
// R-this-round: software-pipelined double-buffered staging (tile (nt,kc) lives
// in buf[kc&1]); one __syncthreads per kc; all ds_read / global_load_lds
// addressing hoisted to per-lane bases + compile-time offsets. Strips live in
// the buf1 region (always dead at selection time: selection follows kc=7,
// and the live prefetched tile (nt+1,0) sits in buf0).
__global__ __launch_bounds__(256, 2) void coarse_kernel(
        const unsigned short* __restrict__ xb,
        const unsigned short* __restrict__ wb,
        float2* __restrict__ candp) {
    __shared__ __attribute__((aligned(16))) char smem[2 * BUFSZ];

    const int tid  = threadIdx.x;
    const int w    = tid >> 6;         // wave id 0..3
    const int l    = tid & 63;
    const int m0   = (blockIdx.x >> 1) * CBM;
    const int half = blockIdx.x & 1;
    const int n0   = half * NHALF;

    const int srow   = l >> 3;               // row within an 8-row staging group
    const int schunk = (l & 7) ^ srow;       // XOR-swizzled source 16B-chunk
    const int mrow   = l & 15;
    const int kq     = l >> 4;               // 0..3
    const int sw     = mrow & 7;

    // per-lane LDS frag-read byte offsets within a buffer.
    // A frag (i,ks): byte = i*2048 + mrow*128 + ((ks*4+kq)^sw)*16
    // B frag (j,ks): byte = 8192 + w*8192 + j*2048 + mrow*128 + ((ks*4+kq)^sw)*16
    const int aoff0 = mrow * 128 + (kq        ^ sw) * 16;
    const int aoff1 = mrow * 128 + ((kq ^ 4)  ^ sw) * 16;
    const int boff0 = 8192 + w * 8192 + mrow * 128 + (kq       ^ sw) * 16;
    const int boff1 = 8192 + w * 8192 + mrow * 128 + ((kq ^ 4) ^ sw) * 16;

    // per-lane global staging sources (advance gB once per nt)
    const unsigned short* gA0 = xb + (size_t)(m0 + w * 16 +     srow) * DIM + schunk * 8;
    const unsigned short* gA1 = xb + (size_t)(m0 + w * 16 + 8 + srow) * DIM + schunk * 8;
    const unsigned short* gB[8];
#pragma unroll
    for (int c = 0; c < 8; ++c)
        gB[c] = wb + (size_t)(n0 + w * 64 + c * 8 + srow) * DIM + schunk * 8;

    // wave-uniform LDS staging destinations (byte offsets within a buffer)
    const int dA = w * 2048;                 // A rows [w*16, w*16+16)
    const int dB = 8192 + w * 8192;          // B rows [w*64, w*64+64)

    auto STAGE = [&](int dstbuf, int koff) {  // koff in bf16 elements
        char* db = smem + dstbuf * BUFSZ;
        __builtin_amdgcn_global_load_lds(
            (const __attribute__((address_space(1))) void*)(gA0 + koff),
            (__attribute__((address_space(3))) void*)(db + dA), 16, 0, 0);
        __builtin_amdgcn_global_load_lds(
            (const __attribute__((address_space(1))) void*)(gA1 + koff),
            (__attribute__((address_space(3))) void*)(db + dA + 1024), 16, 0, 0);
#pragma unroll
        for (int c = 0; c < 8; ++c)
            __builtin_amdgcn_global_load_lds(
                (const __attribute__((address_space(1))) void*)(gB[c] + koff),
                (__attribute__((address_space(3))) void*)(db + dB + c * 1024), 16, 0, 0);
    };

    // strips in buf1 region; per-thread pointers fixed for the whole kernel
    float* const sS  = (float*)(smem + BUFSZ);
    float* const swp = sS + w * (64 * SPITCH) + kq * (4 * SPITCH) + mrow;
    const float4* const srp = (const float4*)(sS + (tid >> 6) * (64 * SPITCH) + (tid & 63) * SPITCH);

    float bv[8]; int bi[8];
#pragma unroll
    for (int k = 0; k < 8; ++k) { bv[k] = -1e30f; bi[k] = k; }

    // prologue: stage tile (0,0) into buf0
    STAGE(0, 0);
    __syncthreads();

    for (int nt = 0; nt < NT_STEPS; ++nt) {
        f32x4 acc[4][4];
#pragma unroll
        for (int i = 0; i < 4; ++i)
#pragma unroll
            for (int j = 0; j < 4; ++j) acc[i][j] = {0.0f, 0.0f, 0.0f, 0.0f};

#pragma unroll
        for (int kc = 0; kc < KC_STEPS; ++kc) {
            // prefetch next tile into the other buffer (issue only; no wait)
            if (kc < KC_STEPS - 1) {
                STAGE((kc + 1) & 1, (kc + 1) * CBK);
            } else if (nt < NT_STEPS - 1) {
#pragma unroll
                for (int c = 0; c < 8; ++c) gB[c] += (size_t)CBN * DIM;
                STAGE(0, 0);
            }

            const int bb = (kc & 1) * BUFSZ;
            bf16x8 a0[4], b0[4], a1[4], b1[4];
#pragma unroll
            for (int i = 0; i < 4; ++i)
                a0[i] = *(const bf16x8*)(smem + bb + aoff0 + i * 2048);
#pragma unroll
            for (int j = 0; j < 4; ++j)
                b0[j] = *(const bf16x8*)(smem + bb + boff0 + j * 2048);
#pragma unroll
            for (int i = 0; i < 4; ++i)
#pragma unroll
                for (int j = 0; j < 4; ++j)
                    acc[i][j] = __builtin_amdgcn_mfma_f32_16x16x32_bf16(
                        a0[i], b0[j], acc[i][j], 0, 0, 0);
#pragma unroll
            for (int i = 0; i < 4; ++i)
                a1[i] = *(const bf16x8*)(smem + bb + aoff1 + i * 2048);
#pragma unroll
            for (int j = 0; j < 4; ++j)
                b1[j] = *(const bf16x8*)(smem + bb + boff1 + j * 2048);
#pragma unroll
            for (int i = 0; i < 4; ++i)
#pragma unroll
                for (int j = 0; j < 4; ++j)
                    acc[i][j] = __builtin_amdgcn_mfma_f32_16x16x32_bf16(
                        a1[i], b1[j], acc[i][j], 0, 0, 0);

            // drains own prefetch (vmcnt 0) + all waves' reads of buf[kc&1]
            __syncthreads();
        }

        // selection: 2 half-strip rounds (32 cols each); strips live in buf1
        // region, which holds the just-consumed (nt,7) tile (dead). The live
        // prefetched tile (nt+1,0) is in buf0 and is not touched.
#pragma unroll
        for (int h = 0; h < 2; ++h) {
#pragma unroll
            for (int i = 0; i < 4; ++i)
#pragma unroll
                for (int jj = 0; jj < 2; ++jj) {
                    const int j = h * 2 + jj;
#pragma unroll
                    for (int r = 0; r < 4; ++r)
                        swp[(i * 16 + r) * SPITCH + jj * 16] = acc[i][j][r];
                }
            __syncthreads();
            // scan: thread (tok = tid&63, qq = tid>>6) scans strip qq's 32 cols
            int ib = n0 + nt * CBN + (tid >> 6) * 64 + h * 32;
#pragma unroll
            for (int c4 = 0; c4 < 8; ++c4) {
                float4 v = srp[c4];
                float m = fmaxf(fmaxf(v.x, v.y), fmaxf(v.z, v.w));
                if (m > bv[7]) {          // rare: divergent branch into insertion
                    top8_insert(v.x, ib + c4 * 4 + 0, bv, bi);
                    top8_insert(v.y, ib + c4 * 4 + 1, bv, bi);
                    top8_insert(v.z, ib + c4 * 4 + 2, bv, bi);
                    top8_insert(v.w, ib + c4 * 4 + 3, bv, bi);
                }
            }
            __syncthreads();   // scans done before strips overwritten / re-staged
        }
    }

    // merge the 4 col-quarter top-8 lists per token; emit (score, idx) pairs.
    // buf0 region is dead now (last tile consumed); reuse for merge arrays.
    float* mv = (float*)smem;              // [64][32]
    int*   mi = (int*)(smem + 8192);       // [64][32]
    {
        int tok = tid & 63, qq = tid >> 6;
#pragma unroll
        for (int k = 0; k < 8; ++k) {
            mv[tok * 32 + qq * 8 + k] = bv[k];
            mi[tok * 32 + qq * 8 + k] = bi[k];
        }
    }
    __syncthreads();
    if (tid < 64) {
        float fv[8]; int fi[8];
#pragma unroll
        for (int k = 0; k < 8; ++k) { fv[k] = -1e30f; fi[k] = k; }
        for (int t = 0; t < 32; ++t) top8_insert(mv[tid * 32 + t], mi[tid * 32 + t], fv, fi);
        float2* cp = candp + ((size_t)(m0 + tid) * 2 + half) * 8;
#pragma unroll
        for (int k = 0; k < 8; ++k) cp[k] = make_float2(fv[k], __int_as_float(fi[k]));
    }
}

// ---------------------------------------------------------------------------
// K3b: merge the two halves' top-8 lists -> final 8 candidate indices/token.
__global__ void merge_kernel(const float2* __restrict__ candp, int* __restrict__ cand8) {
    int tok = blockIdx.x * 256 + threadIdx.x;
    float bv[8]; int bi[8];
#pragma unroll
    for (int k = 0; k < 8; ++k) { bv[k] = -1e30f; bi[k] = k; }
    const float2* cp = candp + (size_t)tok * 16;
#pragma unroll
    for (int t = 0; t < 16; ++t) {
        float2 p = cp[t];
        top8_insert(p.x, __float_as_int(p.y), bv, bi);
    }
    int* o = cand8 + (size_t)tok * 8;
#pragma unroll
    for (int k = 0; k < 8; ++k) o[k] = bi[k];
}

// ---------------------------------------------------------------------------
// K4: f32-replicated dist over 8 candidates (np-exact), gather + MSE partial.
__global__ void refine_kernel(const float* __restrict__ x,
                              const float* __restrict__ embed,
                              const float* __restrict__ whf,
                              const float* __restrict__ t3_f,
                              const int* __restrict__ cand,
                              float* __restrict__ out,
                              double* __restrict__ partial) {
    __shared__ float part[4][32];
    __shared__ double wsum[4];
    const int wid  = threadIdx.x >> 6;
    const int lane = threadIdx.x & 63;
    const int tok  = blockIdx.x * 4 + wid;
    const float* f = x + (size_t)tok * DIM;

    if (lane < 32) {
        int base = (lane >> 3) * 128 + (lane & 7);
        float v = f[base];
        float r = __fmul_rn(v, v);
#pragma unroll
        for (int i = 1; i < 16; ++i) {
            float u = f[base + 8 * i];
            r = __fadd_rn(r, __fmul_rn(u, u));
        }
        part[wid][lane] = r;
    }
    __syncthreads();
    float t1 = pairwise_tree(part[wid]);

    float4 f0 = *(const float4*)(f + lane * 8);
    float4 f1 = *(const float4*)(f + lane * 8 + 4);

    float bd = 1e30f; int bc = 0x7fffffff;
    const int* cp = cand + (size_t)tok * 8;
#pragma unroll
    for (int k = 0; k < 8; ++k) {
        int c = cp[k];
        const float* wh = whf + (size_t)c * DIM + lane * 8;
        float4 w0 = *(const float4*)wh;
        float4 w1 = *(const float4*)(wh + 4);
        double s = (double)f0.x * w0.x + (double)f0.y * w0.y
                 + (double)f0.z * w0.z + (double)f0.w * w0.w
                 + (double)f1.x * w1.x + (double)f1.y * w1.y
                 + (double)f1.z * w1.z + (double)f1.w * w1.w;
#pragma unroll
        for (int off = 32; off > 0; off >>= 1) s += __shfl_xor(s, off);
        float mm = (float)s;
        float dist = __fadd_rn(__fsub_rn(t1, __fmul_rn(2.0f, mm)), t3_f[c]);
        if (dist < bd || (dist == bd && c < bc)) { bd = dist; bc = c; }
    }

    const float* eb = embed + (size_t)bc * DIM;
    double dsum = 0.0;
#pragma unroll
    for (int r = 0; r < DIM / 64; ++r) {
        int d = lane + 64 * r;
        float q = eb[d];
        out[(size_t)tok * DIM + d] = q;   // (quantize + quantize_1)*0.5 == quantize
        double dd = (double)q - (double)f[d];
        dsum += dd * dd;
    }
#pragma unroll
    for (int off = 32; off > 0; off >>= 1) dsum += __shfl_xor(dsum, off);
    if (lane == 0) wsum[wid] = dsum;
    __syncthreads();
    if (threadIdx.x == 0)
        partial[blockIdx.x] = wsum[0] + wsum[1] + wsum[2] + wsum[3];
}

// ---------------------------------------------------------------------------
__global__ void finalize_kernel(const double* __restrict__ partial,
                                float* __restrict__ out) {
    __shared__ double acc[4];
    int tid = threadIdx.x;
    double s = 0.0;
    for (int i = tid; i < N_TOK / 4; i += 256) s += partial[i];
#pragma unroll
    for (int off = 32; off > 0; off >>= 1) s += __shfl_xor(s, off);
    if ((tid & 63) == 0) acc[tid >> 6] = s;
    __syncthreads();
    if (tid == 0)
        out[(size_t)N_TOK * DIM] =
            (float)((acc[0] + acc[1] + acc[2] + acc[3]) * (1.0 / ((double)N_TOK * DIM)));
}

// ---------------------------------------------------------------------------
extern "C" void kernel_launch(void* const* d_in, const int* in_sizes, int n_in,
                              void* d_out, int out_size, void* d_ws, size_t ws_size,
                              hipStream_t stream) {
    const float* x     = (const float*)d_in[0];   // [32768, 512]
    const float* embed = (const float*)d_in[1];   // [4096, 512]
    float* out = (float*)d_out;                   // 16777216 + 1 floats

    char* wsb = (char*)d_ws;
    size_t off = 0;
    double* partial = (double*)(wsb + off); off += 65536;            // 8192 f64
    float*  n_f     = (float*) (wsb + off); off += 16384;
    float*  t3_f    = (float*) (wsb + off); off += 16384;
    float2* candp   = (float2*)(wsb + off); off += (size_t)N_TOK * 16 * 8;  // 4 MB
    int*    cand8   = (int*)   (wsb + off); off += (size_t)N_TOK * 8 * 4;   // 1 MB
    unsigned short* xb = (unsigned short*)(wsb + off); off += (size_t)N_TOK * DIM * 2;  // 32 MB
    unsigned short* wb = (unsigned short*)(wsb + off); off += (size_t)N_CODE * DIM * 2; // 4 MB
    float*  whf     = (float*) (wsb + off);                                  // 8 MB

    xcvt_kernel    <<<16384, 256, 0, stream>>>(x, xb);
    norms_kernel   <<<N_CODE, 64, 0, stream>>>(embed, n_f, t3_f);
    wcvt_kernel    <<<2048, 256, 0, stream>>>(embed, n_f, whf, wb);
    coarse_kernel  <<<(N_TOK / CBM) * 2, 256, 0, stream>>>(xb, wb, candp);
    merge_kernel   <<<N_TOK / 256, 256, 0, stream>>>(candp, cand8);
    refine_kernel  <<<N_TOK / 4, 256, 0, stream>>>(x, embed, whf, t3_f, cand8, out, partial);
    finalize_kernel<<<1, 256, 0, stream>>>(partial, out);
}